// Round 3
// baseline (464.847 us; speedup 1.0000x reference)
//
#include <hip/hip_runtime.h>
#include <hip/hip_bf16.h>
#include <stdint.h>

#define S_LEN 4096
#define DMODEL 512
#define NHEAD 8
#define DHEAD 64
#define NTOK 8192

typedef unsigned short ushort_t;
typedef __attribute__((ext_vector_type(8))) short short8;
typedef __attribute__((ext_vector_type(4))) float f32x4;
typedef unsigned long long u64;
typedef __attribute__((ext_vector_type(2))) unsigned uint2v;

__device__ __forceinline__ float bf2f(ushort_t h) {
    union { unsigned u; float f; } c; c.u = ((unsigned)h) << 16; return c.f;
}
__device__ __forceinline__ ushort_t f2bf(float f) {
    union { float f; unsigned u; } c; c.f = f;
    unsigned u = c.u + 0x7fffu + ((c.u >> 16) & 1u);
    return (ushort_t)(u >> 16);
}
// async global->LDS, 16B/lane; LDS dest MUST be a wave-uniform expression
// not derived from threadIdx (R10 lesson: wave-indexed LDS base -> ~27x stall).
__device__ __forceinline__ void glds16(const ushort_t* g, ushort_t* l) {
    __builtin_amdgcn_global_load_lds(
        (const __attribute__((address_space(1))) unsigned int*)g,
        (__attribute__((address_space(3))) unsigned int*)l, 16, 0, 0);
}

// ---------------- mask -> bit words ----------------
__global__ __launch_bounds__(256) void maskbits_kernel(const int* __restrict__ mask,
        u64* __restrict__ mb) {
    size_t id = (size_t)blockIdx.x * 256 + threadIdx.x;
    int v = mask[id];
    u64 bits = __ballot(v != 0);
    if ((threadIdx.x & 63) == 0) mb[id >> 6] = bits;
}

// ---------------- all weight transposes in one launch ----------------
__global__ __launch_bounds__(256) void wtrans_all(const float* __restrict__ wq,
        const float* __restrict__ wk, const float* __restrict__ wv,
        const float* __restrict__ wo, const float* __restrict__ w1,
        const float* __restrict__ w2,
        ushort_t* wqT, ushort_t* wkT, ushort_t* wvT, ushort_t* woT,
        ushort_t* w1T, ushort_t* w2T) {
    __shared__ __attribute__((aligned(16))) ushort_t t[64][72];
    int z = blockIdx.z;
    const float* src; ushort_t* dst; int R, C;
    switch (z) {
        case 0: src = wq; dst = wqT; R = 512;  C = 512;  break;
        case 1: src = wk; dst = wkT; R = 512;  C = 512;  break;
        case 2: src = wv; dst = wvT; R = 512;  C = 512;  break;
        case 3: src = wo; dst = woT; R = 512;  C = 512;  break;
        case 4: src = w1; dst = w1T; R = 512;  C = 2048; break;
        default: src = w2; dst = w2T; R = 2048; C = 512; break;
    }
    int r0 = blockIdx.x * 64, c0 = blockIdx.y * 64;
    if (r0 >= R || c0 >= C) return;
    int tid = threadIdx.x;
    for (int i = tid; i < 4096; i += 256) {
        int r = i >> 6, c = i & 63;
        t[r][c] = f2bf(src[(size_t)(r0 + r) * C + c0 + c]);
    }
    __syncthreads();
    for (int i = tid; i < 512; i += 256) {
        int c = i >> 3, rb = i & 7;
        short8 vv;
#pragma unroll
        for (int j = 0; j < 8; j++) ((ushort_t*)&vv)[j] = t[rb * 8 + j][c];
        *(short8*)(dst + (size_t)(c0 + c) * R + r0 + rb * 8) = vv;
    }
}

// ---------------- LayerNorm: f32 in, bf16 out; 4 tokens/block ----------------
__global__ __launch_bounds__(256) void ln_f32(const float* __restrict__ x,
        const float* __restrict__ ga, const float* __restrict__ be,
        ushort_t* __restrict__ out) {
    int tok = blockIdx.x * 4 + (threadIdx.x >> 6);
    int lane = threadIdx.x & 63;
    const float* xr = x + (size_t)tok * DMODEL + lane * 8;
    f32x4 v0 = *(const f32x4*)xr;
    f32x4 v1 = *(const f32x4*)(xr + 4);
    float f[8];
    float s = 0.f, s2 = 0.f;
#pragma unroll
    for (int i = 0; i < 8; i++) {
        f[i] = (i < 4) ? v0[i] : v1[i - 4];
        s += f[i]; s2 += f[i] * f[i];
    }
#pragma unroll
    for (int off = 1; off < 64; off <<= 1) {
        s += __shfl_xor(s, off);
        s2 += __shfl_xor(s2, off);
    }
    float mean = s * (1.f / DMODEL);
    float var = (s2 - (float)DMODEL * mean * mean) * (1.f / (DMODEL - 1));
    var = fmaxf(var, 0.f);
    float inv = 1.f / (sqrtf(var) + 1e-6f);   // torch: eps added to std, ddof=1
    short8 o;
#pragma unroll
    for (int i = 0; i < 8; i++) {
        float val = ga[lane * 8 + i] * (f[i] - mean) * inv + be[lane * 8 + i];
        ((ushort_t*)&o)[i] = f2bf(val);
    }
    *(short8*)(out + (size_t)tok * DMODEL + lane * 8) = o;
}

// ---------------- per-head V transpose: V[b,s,h*64+d] -> VT[bh][d][s] ----------------
__global__ __launch_bounds__(256) void vtrans(const ushort_t* __restrict__ V,
        ushort_t* __restrict__ VT) {
    __shared__ __attribute__((aligned(16))) ushort_t t[64][72];
    int s0 = blockIdx.x * 64;
    int bh = blockIdx.y;
    int b = bh >> 3, h = bh & 7;
    int tid = threadIdx.x;
    const ushort_t* src = V + ((size_t)b * S_LEN + s0) * DMODEL + h * DHEAD;
    for (int i = tid; i < 512; i += 256) {
        int r = i >> 3, cb = i & 7;
        *(short8*)&t[r][cb * 8] = *(const short8*)(src + (size_t)r * DMODEL + cb * 8);
    }
    __syncthreads();
    ushort_t* dst = VT + (size_t)bh * DHEAD * S_LEN;
    for (int i = tid; i < 512; i += 256) {
        int d = i >> 3, rb = i & 7;
        short8 vv;
#pragma unroll
        for (int j = 0; j < 8; j++) ((ushort_t*)&vv)[j] = t[rb * 8 + j][d];
        *(short8*)(dst + (size_t)d * S_LEN + s0 + rb * 8) = vv;
    }
}

// ---------------- bf16 GEMM core, templated tile: block = (32*MW) x (32*NW) ----------------
template <int MW, int NW>
__device__ __forceinline__ void gemm_body(const ushort_t* __restrict__ A,
        const ushort_t* __restrict__ BT, void* __restrict__ C,
        int N, int K, float scale, const float* __restrict__ bias,
        const float* __restrict__ res, int relu, int cf32,
        ushort_t* As, ushort_t* Bs, int m0, int n0, int aoff, int coff) {
    int tid = threadIdx.x;
    int wave = tid >> 6, lane = tid & 63;
    int wm = wave >> 1, wn = wave & 1;
    int lr = lane & 15, lg = lane >> 4;
    int srow = lane >> 2, spos = lane & 3;
    int swz = (spos ^ ((srow >> 1) & 3)) * 8;
    int rdw = (lr >> 1) & 3;
    f32x4 acc[MW][NW];
#pragma unroll
    for (int i = 0; i < MW; i++)
#pragma unroll
        for (int j = 0; j < NW; j++) acc[i][j] = (f32x4){0.f, 0.f, 0.f, 0.f};

    const ushort_t* Ag = A + (size_t)(m0 - aoff) * K;
    const ushort_t* Bg = BT + (size_t)n0 * K;

    for (int k0 = 0; k0 < K; k0 += 32) {
        __syncthreads();
        for (int ia = wave; ia < 2 * MW; ia += 4)
            glds16(Ag + (size_t)(ia * 16 + srow) * K + k0 + swz, As + ia * 16 * 32);
        for (int ib = wave; ib < 2 * NW; ib += 4)
            glds16(Bg + (size_t)(ib * 16 + srow) * K + k0 + swz, Bs + ib * 16 * 32);
        __syncthreads();
        short8 af[MW], bfv[NW];
#pragma unroll
        for (int t = 0; t < MW; t++)
            af[t] = *(const short8*)(As + (wm * 16 * MW + t * 16 + lr) * 32 + (lg ^ rdw) * 8);
#pragma unroll
        for (int t = 0; t < NW; t++)
            bfv[t] = *(const short8*)(Bs + (wn * 16 * NW + t * 16 + lr) * 32 + (lg ^ rdw) * 8);
#pragma unroll
        for (int i = 0; i < MW; i++)
#pragma unroll
            for (int j = 0; j < NW; j++)
                acc[i][j] = __builtin_amdgcn_mfma_f32_16x16x32_bf16(af[i], bfv[j], acc[i][j], 0, 0, 0);
    }
#pragma unroll
    for (int i = 0; i < MW; i++) {
        int row = m0 + wm * 16 * MW + i * 16 + lg * 4;
#pragma unroll
        for (int j = 0; j < NW; j++) {
            int col = n0 + wn * 16 * NW + j * 16 + lr;
            float bb = bias ? bias[col] : 0.f;
#pragma unroll
            for (int r = 0; r < 4; r++) {
                float v = acc[i][j][r] * scale + bb;
                if (relu) v = fmaxf(v, 0.f);
                if (res) v += res[(size_t)(row + r) * N + col];
                size_t cidx = (size_t)(row + r - coff) * N + col;
                if (cf32) ((float*)C)[cidx] = v;
                else      ((ushort_t*)C)[cidx] = f2bf(v);
            }
        }
    }
}

// 128x128 tile (same body as gemm_qkv, with full epilogue options)
__global__ __launch_bounds__(256) void gemm_bt128(const ushort_t* __restrict__ A,
        const ushort_t* __restrict__ BT, void* __restrict__ C,
        int N, int K, float scale, const float* bias, const float* res, int relu,
        int cf32, int m_base, int aoff, int coff) {
    __shared__ __attribute__((aligned(16))) ushort_t As[128 * 32];
    __shared__ __attribute__((aligned(16))) ushort_t Bs[128 * 32];
    gemm_body<4, 4>(A, BT, C, N, K, scale, bias, res, relu, cf32, As, Bs,
                    m_base + blockIdx.x * 128, blockIdx.y * 128, aoff, coff);
}

// 128x64 tile (for N=512 GEMMs: keeps grid >= 256 blocks)
__global__ __launch_bounds__(256) void gemm_bt128x64(const ushort_t* __restrict__ A,
        const ushort_t* __restrict__ BT, void* __restrict__ C,
        int N, int K, float scale, const float* bias, const float* res, int relu,
        int cf32, int m_base, int aoff, int coff) {
    __shared__ __attribute__((aligned(16))) ushort_t As[128 * 32];
    __shared__ __attribute__((aligned(16))) ushort_t Bs[64 * 32];
    gemm_body<4, 2>(A, BT, C, N, K, scale, bias, res, relu, cf32, As, Bs,
                    m_base + blockIdx.x * 128, blockIdx.y * 64, aoff, coff);
}

__global__ __launch_bounds__(256) void gemm_qkv(const ushort_t* __restrict__ A,
        const ushort_t* __restrict__ wqT, const ushort_t* __restrict__ wkT,
        const ushort_t* __restrict__ wvT,
        ushort_t* __restrict__ Q, ushort_t* __restrict__ Kb, ushort_t* __restrict__ V) {
    __shared__ __attribute__((aligned(16))) ushort_t As[128 * 32];
    __shared__ __attribute__((aligned(16))) ushort_t Bs[128 * 32];
    int z = blockIdx.z;
    const ushort_t* W = (z == 0) ? wqT : ((z == 1) ? wkT : wvT);
    ushort_t* O = (z == 0) ? Q : ((z == 1) ? Kb : V);
    // fold 1/sqrt(64) AND log2(e) into Q so attn can use raw v_exp_f32 (exp2)
    float sc = (z == 0) ? 0.18033688011112042f : 1.f;
    gemm_body<4, 4>(A, W, O, DMODEL, DMODEL, sc, nullptr, nullptr, 0, 0, As, Bs,
                    blockIdx.x * 128, blockIdx.y * 128, 0, 0);
}

// ---------------- flash attention v4: in-register P transpose, no Pw LDS ----
// 32 q/wave, 2 waves/block, key-split x2 (partial O + denom, combined later).
// S-output fragment (4 keys/lane, C-layout) -> PV A-operand fragment
// (8 keys/lane) via v_permlane32_swap + v_permlane16_swap (gfx950 MFMA-assist
// ops): removes the P LDS write->read chain entirely. Denominator folded into
// MFMA with an all-ones B fragment: den[u][r] lands directly in the
// O-accumulator row layout (no per-iter VALU adds, no epilogue shuffles).
// LDS = 16 KB -> 10 blocks/CU capacity, full 8/CU grid resident.
__global__ __launch_bounds__(128, 4) void attn_kernel(const ushort_t* __restrict__ Q,
        const ushort_t* __restrict__ K, const ushort_t* __restrict__ VT,
        const unsigned* __restrict__ mb32, ushort_t* __restrict__ Opart,
        float* __restrict__ lpart) {
    __shared__ __attribute__((aligned(16))) ushort_t Ks[2][32 * 64];  // keys x d
    __shared__ __attribute__((aligned(16))) ushort_t Vs[2][64 * 32];  // d x keys
    int qt = blockIdx.x, h = blockIdx.y, zz = blockIdx.z;
    int b = zz >> 1, half = zz & 1;
    int tid = threadIdx.x;
    int wv = __builtin_amdgcn_readfirstlane(tid >> 6);   // SGPR wave id
    int lane = tid & 63;
    int lr = lane & 15, lg = lane >> 4;
    size_t tokbase = (size_t)b * S_LEN;
    int q0 = qt * 64 + wv * 32;
    int k0 = half * (S_LEN / 2);

    const ushort_t* Qp = Q + (tokbase + q0) * DMODEL + h * DHEAD;
    short8 qf[2][2];
#pragma unroll
    for (int u = 0; u < 2; u++) {
        qf[u][0] = *(const short8*)(Qp + (size_t)(u * 16 + lr) * DMODEL + lg * 8);
        qf[u][1] = *(const short8*)(Qp + (size_t)(u * 16 + lr) * DMODEL + 32 + lg * 8);
    }
    f32x4 o[2][4];
#pragma unroll
    for (int u = 0; u < 2; u++)
#pragma unroll
        for (int td = 0; td < 4; td++) o[u][td] = (f32x4){0.f, 0.f, 0.f, 0.f};
    f32x4 den[2] = {(f32x4){0.f, 0.f, 0.f, 0.f}, (f32x4){0.f, 0.f, 0.f, 0.f}};
    short8 ones8;
#pragma unroll
    for (int j = 0; j < 8; j++) ((ushort_t*)&ones8)[j] = 0x3F80;  // bf16 1.0

    int srow = lane >> 3, spos = lane & 7;      // K staging: 8 rows x 8 chunks
    int srow2 = lane >> 2, spos2 = lane & 3;    // V staging: 16 rows x 4 chunks
    int kst = (spos ^ srow) * 8;
    int vst = (spos2 ^ ((srow2 >> 1) & 3)) * 8;
    int rdk = lr & 7;
    int rdv = (lr >> 1) & 3;

    const ushort_t* kgl = K + (tokbase + k0) * DMODEL + h * DHEAD
                          + (size_t)srow * DMODEL + kst;
    const ushort_t* vgl = VT + (size_t)(b * NHEAD + h) * DHEAD * S_LEN
                          + (size_t)srow2 * S_LEN + k0 + vst;
    const unsigned* mr0 = mb32 + (size_t)(q0 + lr) * 128 + half * 64;
    const unsigned* mr1 = mb32 + (size_t)(q0 + 16 + lr) * 128 + half * 64;

    // prologue: mask + tile 0 into buf 0 (wave-split loads)
    unsigned w0 = mr0[0], w1 = mr1[0];
    if (wv == 0) {
        glds16(kgl + (size_t)0 * DMODEL, &Ks[0][0 * 64]);
        glds16(kgl + (size_t)8 * DMODEL, &Ks[0][8 * 64]);
        glds16(vgl + (size_t)0 * S_LEN, &Vs[0][0 * 32]);
        glds16(vgl + (size_t)16 * S_LEN, &Vs[0][16 * 32]);
    } else {
        glds16(kgl + (size_t)16 * DMODEL, &Ks[0][16 * 64]);
        glds16(kgl + (size_t)24 * DMODEL, &Ks[0][24 * 64]);
        glds16(vgl + (size_t)32 * S_LEN, &Vs[0][32 * 32]);
        glds16(vgl + (size_t)48 * S_LEN, &Vs[0][48 * 32]);
    }

    const int NIT = (S_LEN / 2) / 32;   // 64
#pragma unroll 1
    for (int kt = 0; kt < NIT; kt++) {
        int cur = kt & 1;
        __builtin_amdgcn_s_barrier();   // partner done reading buf cur^1 -> may overwrite
        unsigned nw0 = 0, nw1 = 0;
        if (kt + 1 < NIT) {
            nw0 = mr0[kt + 1];
            nw1 = mr1[kt + 1];
            const ushort_t* kgn = kgl + (size_t)(kt + 1) * 32 * DMODEL;
            const ushort_t* vgn = vgl + (kt + 1) * 32;
            if (wv == 0) {
                glds16(kgn + (size_t)0 * DMODEL, &Ks[cur ^ 1][0 * 64]);
                glds16(kgn + (size_t)8 * DMODEL, &Ks[cur ^ 1][8 * 64]);
                glds16(vgn + (size_t)0 * S_LEN, &Vs[cur ^ 1][0 * 32]);
                glds16(vgn + (size_t)16 * S_LEN, &Vs[cur ^ 1][16 * 32]);
            } else {
                glds16(kgn + (size_t)16 * DMODEL, &Ks[cur ^ 1][16 * 64]);
                glds16(kgn + (size_t)24 * DMODEL, &Ks[cur ^ 1][24 * 64]);
                glds16(vgn + (size_t)32 * S_LEN, &Vs[cur ^ 1][32 * 32]);
                glds16(vgn + (size_t)48 * S_LEN, &Vs[cur ^ 1][48 * 32]);
            }
            __builtin_amdgcn_s_waitcnt(3958);   // vmcnt(6): own tile-kt glds drained
        } else {
            __builtin_amdgcn_s_waitcnt(3952);   // vmcnt(0)
        }
        __builtin_amdgcn_s_barrier();   // partner's tile-kt loads visible in LDS
        const ushort_t* Kb_ = Ks[cur];
        const ushort_t* Vb_ = Vs[cur];
        // S^T = K Q^T : D[key][q]; col=q=u*16+lr, row=key=t*16+lg*4+r
        f32x4 s[2][2];
#pragma unroll
        for (int t = 0; t < 2; t++) {
            const ushort_t* kr = Kb_ + (t * 16 + lr) * 64;
            short8 kf0 = *(const short8*)(kr + ((lg ^ rdk) * 8));
            short8 kf1 = *(const short8*)(kr + (((lg + 4) ^ rdk) * 8));
#pragma unroll
            for (int u = 0; u < 2; u++) {
                f32x4 z = (f32x4){0.f, 0.f, 0.f, 0.f};
                z = __builtin_amdgcn_mfma_f32_16x16x32_bf16(kf0, qf[u][0], z, 0, 0, 0);
                z = __builtin_amdgcn_mfma_f32_16x16x32_bf16(kf1, qf[u][1], z, 0, 0, 0);
                s[t][u] = z;
            }
        }
        // exp2 (log2e folded into Q), mask-zero
#pragma unroll
        for (int u = 0; u < 2; u++) {
            unsigned wq = (u ? w1 : w0) >> (lg * 4);
#pragma unroll
            for (int r = 0; r < 4; r++) {
                float p0, p1;
                asm("v_exp_f32 %0, %1\n\ts_nop 0" : "=v"(p0) : "v"(s[0][u][r]));
                asm("v_exp_f32 %0, %1\n\ts_nop 0" : "=v"(p1) : "v"(s[1][u][r]));
                p0 = ((wq >> r) & 1u) ? p0 : 0.f;
                p1 = ((wq >> (16 + r)) & 1u) ? p1 : 0.f;
                s[0][u][r] = p0; s[1][u][r] = p1;
            }
        }
        // V fragments (shared by both q-groups)
        short8 vf[4];
#pragma unroll
        for (int td = 0; td < 4; td++)
            vf[td] = *(const short8*)(Vb_ + (td * 16 + lr) * 32 + ((lg ^ rdv) * 8));
        // In-register P transpose: C-layout (4 keys @ lg*4, per t) ->
        // A-operand layout (8 consecutive keys @ g*8). Verified mapping:
        //   swap32(c0,c1): d'={low: c0 own | high: c1 of lane-32}
        //                  s'={low: c0 of lane+32 | high: c1 own}
        //   swap16(A,B):   rows 1,3 of A <- rows 0,2 of B; rows 0,2 of B <- rows 1,3 of A
        // final words {A'0, A'1, B'0, B'1} = keys g*8 .. g*8+7 for q = lr.
#pragma unroll
        for (int u = 0; u < 2; u++) {
            unsigned c00, c01, c10, c11;
            asm("v_cvt_pk_bf16_f32 %0, %1, %2" : "=v"(c00) : "v"(s[0][u][0]), "v"(s[0][u][1]));
            asm("v_cvt_pk_bf16_f32 %0, %1, %2" : "=v"(c01) : "v"(s[0][u][2]), "v"(s[0][u][3]));
            asm("v_cvt_pk_bf16_f32 %0, %1, %2" : "=v"(c10) : "v"(s[1][u][0]), "v"(s[1][u][1]));
            asm("v_cvt_pk_bf16_f32 %0, %1, %2" : "=v"(c11) : "v"(s[1][u][2]), "v"(s[1][u][3]));
            auto r0 = __builtin_amdgcn_permlane32_swap(c00, c10, false, false);
            auto r1 = __builtin_amdgcn_permlane32_swap(c01, c11, false, false);
            auto p0 = __builtin_amdgcn_permlane16_swap(r0[0], r0[1], false, false);
            auto p1 = __builtin_amdgcn_permlane16_swap(r1[0], r1[1], false, false);
            union { unsigned u32[4]; short8 s8; } pk;
            pk.u32[0] = p0[0]; pk.u32[1] = p1[0]; pk.u32[2] = p0[1]; pk.u32[3] = p1[1];
            short8 pf = pk.s8;
            // O += P V ; den += P * ones (denominator in O-row layout)
#pragma unroll
            for (int td = 0; td < 4; td++)
                o[u][td] = __builtin_amdgcn_mfma_f32_16x16x32_bf16(pf, vf[td], o[u][td], 0, 0, 0);
            den[u] = __builtin_amdgcn_mfma_f32_16x16x32_bf16(pf, ones8, den[u], 0, 0, 0);
        }
        w0 = nw0; w1 = nw1;
    }
    // epilogue: store partial denom (row layout: q = u*16 + lg*4 + r, all 16
    // col-lanes hold copies -> store from lr==0) and unnormalized partial O.
    float* lp = lpart + (size_t)half * (NHEAD * 2 * S_LEN)
                + (size_t)(b * NHEAD + h) * S_LEN + q0;
    if (lr == 0) {
#pragma unroll
        for (int u = 0; u < 2; u++)
#pragma unroll
            for (int r = 0; r < 4; r++)
                lp[u * 16 + lg * 4 + r] = den[u][r];
    }
    ushort_t* Op = Opart + (size_t)half * NTOK * DMODEL;
#pragma unroll
    for (int u = 0; u < 2; u++) {
        size_t rowb = (tokbase + q0 + u * 16 + lg * 4) * DMODEL + h * DHEAD;
#pragma unroll
        for (int td = 0; td < 4; td++) {
            int cc = td * 16 + lr;
            Op[rowb + 0 * DMODEL + cc] = f2bf(o[u][td][0]);
            Op[rowb + 1 * DMODEL + cc] = f2bf(o[u][td][1]);
            Op[rowb + 2 * DMODEL + cc] = f2bf(o[u][td][2]);
            Op[rowb + 3 * DMODEL + cc] = f2bf(o[u][td][3]);
        }
    }
}

// ---------------- combine the two key-halves: ctx = (Oa+Ob)/(la+lb) ----------------
__global__ __launch_bounds__(256) void attn_combine(const ushort_t* __restrict__ Oa,
        const ushort_t* __restrict__ Ob, const float* __restrict__ la,
        const float* __restrict__ lb, ushort_t* __restrict__ ctx) {
    size_t idx = ((size_t)blockIdx.x * 256 + threadIdx.x) * 8;
    size_t tok = idx >> 9;
    int col = (int)(idx & 511);
    int h = col >> 6;
    int b = (int)(tok >> 12);
    int q = (int)(tok & 4095);
    size_t li = (size_t)(b * NHEAD + h) * S_LEN + q;
    float inv = 1.f / (la[li] + lb[li]);
    short8 va = *(const short8*)(Oa + idx);
    short8 vb = *(const short8*)(Ob + idx);
    short8 oo;
#pragma unroll
    for (int j = 0; j < 8; j++)
        ((ushort_t*)&oo)[j] = f2bf((bf2f(((const ushort_t*)&va)[j])
                                  + bf2f(((const ushort_t*)&vb)[j])) * inv);
    *(short8*)(ctx + idx) = oo;
}

extern "C" void kernel_launch(void* const* d_in, const int* in_sizes, int n_in,
                              void* d_out, int out_size, void* d_ws, size_t ws_size,
                              hipStream_t stream) {
    (void)in_sizes; (void)n_in; (void)out_size; (void)ws_size;
    const float* x    = (const float*)d_in[0];
    const int*   mask = (const int*)d_in[1];
    const float* w_q  = (const float*)d_in[2];
    const float* w_k  = (const float*)d_in[3];
    const float* w_v  = (const float*)d_in[4];
    const float* w_o  = (const float*)d_in[5];
    const float* w1   = (const float*)d_in[6];
    const float* b1   = (const float*)d_in[7];
    const float* w2   = (const float*)d_in[8];
    const float* b2   = (const float*)d_in[9];
    const float* l1a  = (const float*)d_in[10];
    const float* l1b  = (const float*)d_in[11];
    const float* l2a  = (const float*)d_in[12];
    const float* l2b  = (const float*)d_in[13];

    char* ws = (char*)d_ws;
    const size_t MB = 1024 * 1024;
    const size_t KB = 1024;
    // ---- layout, <= 54 MB ----
    ushort_t* w1T  = (ushort_t*)(ws + 0);               // 2MB
    ushort_t* w2T  = (ushort_t*)(ws + 2 * MB);          // 2MB
    ushort_t* wqT  = (ushort_t*)(ws + 4 * MB);          // 512KB (dead after QKV -> lpart)
    ushort_t* wkT  = (ushort_t*)(ws + 4 * MB + 512 * KB);
    ushort_t* wvT  = (ushort_t*)(ws + 5 * MB);
    ushort_t* woT  = (ushort_t*)(ws + 5 * MB + 512 * KB);
    ushort_t* ff1  = (ushort_t*)(ws + 6 * MB);          // 16MB: Opart (attn), then FFN chunk
    ushort_t* h    = (ushort_t*)(ws + 22 * MB);         // 8MB: h / VTb / h2
    ushort_t* VTb  = h;
    ushort_t* h2   = h;
    ushort_t* Qb   = (ushort_t*)(ws + 30 * MB);         // 8MB
    float*    x2f  = (float*)(ws + 30 * MB);            // 16MB (after attn)
    ushort_t* Kb   = (ushort_t*)(ws + 38 * MB);         // 8MB
    ushort_t* Vb   = (ushort_t*)(ws + 46 * MB);         // 8MB: V, then ctx
    ushort_t* ctx  = Vb;
    ushort_t* Opart = ff1;                              // 2 x 8MB bf16 partials
    float*    lpart = (float*)wqT;                      // 2 x 256KB f32 partial denoms
    u64*      mb   = (u64*)d_out;                       // 2MB scratch in d_out
    float*    out  = (float*)d_out;

    dim3 blk(256);
    maskbits_kernel<<<dim3(65536), blk, 0, stream>>>(mask, mb);
    wtrans_all<<<dim3(32, 32, 6), blk, 0, stream>>>(w_q, w_k, w_v, w_o, w1, w2,
            wqT, wkT, wvT, woT, w1T, w2T);
    ln_f32<<<dim3(NTOK / 4), blk, 0, stream>>>(x, l1a, l1b, h);
    gemm_qkv<<<dim3(64, 4, 3), blk, 0, stream>>>(h, wqT, wkT, wvT, Qb, Kb, Vb);
    vtrans<<<dim3(64, 16), blk, 0, stream>>>(Vb, VTb);
    attn_kernel<<<dim3(64, 8, 4), dim3(128), 0, stream>>>(Qb, Kb, VTb,
            (const unsigned*)mb, Opart, lpart);
    attn_combine<<<dim3(2048), blk, 0, stream>>>(Opart,
            Opart + (size_t)NTOK * DMODEL, lpart, lpart + NHEAD * 2 * S_LEN, ctx);
    gemm_bt128<<<dim3(64, 4), blk, 0, stream>>>(ctx, woT, x2f, 512, 512, 1.f,
            nullptr, x, 0, 1, 0, 0, 0);
    ln_f32<<<dim3(NTOK / 4), blk, 0, stream>>>(x2f, l2a, l2b, h2);
    gemm_bt128<<<dim3(32, 16), blk, 0, stream>>>(h2, w1T, ff1, 2048, 512, 1.f,
            b1, nullptr, 1, 0, 0, 0, 0);
    gemm_bt128x64<<<dim3(32, 8), blk, 0, stream>>>(ff1, w2T, out, 512, 2048, 1.f,
            b2, x2f, 0, 1, 0, 0, 0);
    gemm_bt128<<<dim3(32, 16), blk, 0, stream>>>(h2, w1T, ff1, 2048, 512, 1.f,
            b1, nullptr, 1, 0, 4096, 0, 4096);
    gemm_bt128x64<<<dim3(32, 8), blk, 0, stream>>>(ff1, w2T, out, 512, 2048, 1.f,
            b2, x2f, 0, 1, 4096, 4096, 0);
}

// Round 4
// 411.413 us; speedup vs baseline: 1.1299x; 1.1299x over previous
//
#include <hip/hip_runtime.h>
#include <hip/hip_bf16.h>
#include <stdint.h>

#define S_LEN 4096
#define DMODEL 512
#define NHEAD 8
#define DHEAD 64
#define NTOK 8192

typedef unsigned short ushort_t;
typedef __attribute__((ext_vector_type(8))) short short8;
typedef __attribute__((ext_vector_type(4))) float f32x4;
typedef unsigned long long u64;
typedef __attribute__((ext_vector_type(2))) unsigned uint2v;

__device__ __forceinline__ float bf2f(ushort_t h) {
    union { unsigned u; float f; } c; c.u = ((unsigned)h) << 16; return c.f;
}
__device__ __forceinline__ ushort_t f2bf(float f) {
    union { float f; unsigned u; } c; c.f = f;
    unsigned u = c.u + 0x7fffu + ((c.u >> 16) & 1u);
    return (ushort_t)(u >> 16);
}
// async global->LDS, 16B/lane; LDS dest MUST be a wave-uniform expression
// not derived from threadIdx (R10 lesson: wave-indexed LDS base -> ~27x stall).
__device__ __forceinline__ void glds16(const ushort_t* g, ushort_t* l) {
    __builtin_amdgcn_global_load_lds(
        (const __attribute__((address_space(1))) unsigned int*)g,
        (__attribute__((address_space(3))) unsigned int*)l, 16, 0, 0);
}

// ---------------- mask -> bit words ----------------
__global__ __launch_bounds__(256) void maskbits_kernel(const int* __restrict__ mask,
        u64* __restrict__ mb) {
    size_t id = (size_t)blockIdx.x * 256 + threadIdx.x;
    int v = mask[id];
    u64 bits = __ballot(v != 0);
    if ((threadIdx.x & 63) == 0) mb[id >> 6] = bits;
}

// ---------------- mask bits -> lane-transposed words for SGPR cndmask ----------
// mbT[gq][kt][t*4+r]: u64 whose bit[lane] = mask[gq*16+(lane&15)][kt*32+t*16+(lane>>4)*4+r]
// (lane = lg*16+lr). One word == the exact per-lane mask of one attn score
// element (u,t,r); attn applies it with a single v_cndmask_b32 (sgpr pair).
// Reads the 2MB packed mb (L2-resident), not the 64MB int mask.
__global__ __launch_bounds__(256) void masktrans_kernel(const u64* __restrict__ mb,
        u64* __restrict__ mbT) {
    int wid = (int)(((size_t)blockIdx.x * 256 + threadIdx.x) >> 6);
    int lane = threadIdx.x & 63;
    int gq = wid >> 7, kt = wid & 127;
    int lr = lane & 15, lg = lane >> 4;
    int row = gq * 16 + lr;
    u64* outp = mbT + ((size_t)gq * 128 + kt) * 8;
#pragma unroll
    for (int t = 0; t < 2; t++)
#pragma unroll
        for (int r = 0; r < 4; r++) {
            int col = kt * 32 + t * 16 + lg * 4 + r;
            u64 w = mb[(size_t)row * 64 + (col >> 6)];
            u64 bb = __ballot((unsigned)((w >> (col & 63)) & 1));
            if (lane == t * 4 + r) outp[t * 4 + r] = bb;
        }
}

// ---------------- all weight transposes in one launch ----------------
__global__ __launch_bounds__(256) void wtrans_all(const float* __restrict__ wq,
        const float* __restrict__ wk, const float* __restrict__ wv,
        const float* __restrict__ wo, const float* __restrict__ w1,
        const float* __restrict__ w2,
        ushort_t* wqT, ushort_t* wkT, ushort_t* wvT, ushort_t* woT,
        ushort_t* w1T, ushort_t* w2T) {
    __shared__ __attribute__((aligned(16))) ushort_t t[64][72];
    int z = blockIdx.z;
    const float* src; ushort_t* dst; int R, C;
    switch (z) {
        case 0: src = wq; dst = wqT; R = 512;  C = 512;  break;
        case 1: src = wk; dst = wkT; R = 512;  C = 512;  break;
        case 2: src = wv; dst = wvT; R = 512;  C = 512;  break;
        case 3: src = wo; dst = woT; R = 512;  C = 512;  break;
        case 4: src = w1; dst = w1T; R = 512;  C = 2048; break;
        default: src = w2; dst = w2T; R = 2048; C = 512; break;
    }
    int r0 = blockIdx.x * 64, c0 = blockIdx.y * 64;
    if (r0 >= R || c0 >= C) return;
    int tid = threadIdx.x;
    for (int i = tid; i < 4096; i += 256) {
        int r = i >> 6, c = i & 63;
        t[r][c] = f2bf(src[(size_t)(r0 + r) * C + c0 + c]);
    }
    __syncthreads();
    for (int i = tid; i < 512; i += 256) {
        int c = i >> 3, rb = i & 7;
        short8 vv;
#pragma unroll
        for (int j = 0; j < 8; j++) ((ushort_t*)&vv)[j] = t[rb * 8 + j][c];
        *(short8*)(dst + (size_t)(c0 + c) * R + r0 + rb * 8) = vv;
    }
}

// ---------------- LayerNorm: f32 in, bf16 out; 4 tokens/block ----------------
__global__ __launch_bounds__(256) void ln_f32(const float* __restrict__ x,
        const float* __restrict__ ga, const float* __restrict__ be,
        ushort_t* __restrict__ out) {
    int tok = blockIdx.x * 4 + (threadIdx.x >> 6);
    int lane = threadIdx.x & 63;
    const float* xr = x + (size_t)tok * DMODEL + lane * 8;
    f32x4 v0 = *(const f32x4*)xr;
    f32x4 v1 = *(const f32x4*)(xr + 4);
    float f[8];
    float s = 0.f, s2 = 0.f;
#pragma unroll
    for (int i = 0; i < 8; i++) {
        f[i] = (i < 4) ? v0[i] : v1[i - 4];
        s += f[i]; s2 += f[i] * f[i];
    }
#pragma unroll
    for (int off = 1; off < 64; off <<= 1) {
        s += __shfl_xor(s, off);
        s2 += __shfl_xor(s2, off);
    }
    float mean = s * (1.f / DMODEL);
    float var = (s2 - (float)DMODEL * mean * mean) * (1.f / (DMODEL - 1));
    var = fmaxf(var, 0.f);
    float inv = 1.f / (sqrtf(var) + 1e-6f);   // torch: eps added to std, ddof=1
    short8 o;
#pragma unroll
    for (int i = 0; i < 8; i++) {
        float val = ga[lane * 8 + i] * (f[i] - mean) * inv + be[lane * 8 + i];
        ((ushort_t*)&o)[i] = f2bf(val);
    }
    *(short8*)(out + (size_t)tok * DMODEL + lane * 8) = o;
}

// ---------------- per-head V transpose: V[b,s,h*64+d] -> VT[bh][d][s] ----------------
__global__ __launch_bounds__(256) void vtrans(const ushort_t* __restrict__ V,
        ushort_t* __restrict__ VT) {
    __shared__ __attribute__((aligned(16))) ushort_t t[64][72];
    int s0 = blockIdx.x * 64;
    int bh = blockIdx.y;
    int b = bh >> 3, h = bh & 7;
    int tid = threadIdx.x;
    const ushort_t* src = V + ((size_t)b * S_LEN + s0) * DMODEL + h * DHEAD;
    for (int i = tid; i < 512; i += 256) {
        int r = i >> 3, cb = i & 7;
        *(short8*)&t[r][cb * 8] = *(const short8*)(src + (size_t)r * DMODEL + cb * 8);
    }
    __syncthreads();
    ushort_t* dst = VT + (size_t)bh * DHEAD * S_LEN;
    for (int i = tid; i < 512; i += 256) {
        int d = i >> 3, rb = i & 7;
        short8 vv;
#pragma unroll
        for (int j = 0; j < 8; j++) ((ushort_t*)&vv)[j] = t[rb * 8 + j][d];
        *(short8*)(dst + (size_t)d * S_LEN + s0 + rb * 8) = vv;
    }
}

// ---------------- bf16 GEMM core, templated tile: block = (32*MW) x (32*NW) ----------------
template <int MW, int NW>
__device__ __forceinline__ void gemm_body(const ushort_t* __restrict__ A,
        const ushort_t* __restrict__ BT, void* __restrict__ C,
        int N, int K, float scale, const float* __restrict__ bias,
        const float* __restrict__ res, int relu, int cf32,
        ushort_t* As, ushort_t* Bs, int m0, int n0, int aoff, int coff) {
    int tid = threadIdx.x;
    int wave = tid >> 6, lane = tid & 63;
    int wm = wave >> 1, wn = wave & 1;
    int lr = lane & 15, lg = lane >> 4;
    int srow = lane >> 2, spos = lane & 3;
    int swz = (spos ^ ((srow >> 1) & 3)) * 8;
    int rdw = (lr >> 1) & 3;
    f32x4 acc[MW][NW];
#pragma unroll
    for (int i = 0; i < MW; i++)
#pragma unroll
        for (int j = 0; j < NW; j++) acc[i][j] = (f32x4){0.f, 0.f, 0.f, 0.f};

    const ushort_t* Ag = A + (size_t)(m0 - aoff) * K;
    const ushort_t* Bg = BT + (size_t)n0 * K;

    for (int k0 = 0; k0 < K; k0 += 32) {
        __syncthreads();
        for (int ia = wave; ia < 2 * MW; ia += 4)
            glds16(Ag + (size_t)(ia * 16 + srow) * K + k0 + swz, As + ia * 16 * 32);
        for (int ib = wave; ib < 2 * NW; ib += 4)
            glds16(Bg + (size_t)(ib * 16 + srow) * K + k0 + swz, Bs + ib * 16 * 32);
        __syncthreads();
        short8 af[MW], bfv[NW];
#pragma unroll
        for (int t = 0; t < MW; t++)
            af[t] = *(const short8*)(As + (wm * 16 * MW + t * 16 + lr) * 32 + (lg ^ rdw) * 8);
#pragma unroll
        for (int t = 0; t < NW; t++)
            bfv[t] = *(const short8*)(Bs + (wn * 16 * NW + t * 16 + lr) * 32 + (lg ^ rdw) * 8);
#pragma unroll
        for (int i = 0; i < MW; i++)
#pragma unroll
            for (int j = 0; j < NW; j++)
                acc[i][j] = __builtin_amdgcn_mfma_f32_16x16x32_bf16(af[i], bfv[j], acc[i][j], 0, 0, 0);
    }
#pragma unroll
    for (int i = 0; i < MW; i++) {
        int row = m0 + wm * 16 * MW + i * 16 + lg * 4;
#pragma unroll
        for (int j = 0; j < NW; j++) {
            int col = n0 + wn * 16 * NW + j * 16 + lr;
            float bb = bias ? bias[col] : 0.f;
#pragma unroll
            for (int r = 0; r < 4; r++) {
                float v = acc[i][j][r] * scale + bb;
                if (relu) v = fmaxf(v, 0.f);
                if (res) v += res[(size_t)(row + r) * N + col];
                size_t cidx = (size_t)(row + r - coff) * N + col;
                if (cf32) ((float*)C)[cidx] = v;
                else      ((ushort_t*)C)[cidx] = f2bf(v);
            }
        }
    }
}

__global__ __launch_bounds__(256) void gemm_bt64(const ushort_t* __restrict__ A,
        const ushort_t* __restrict__ BT, void* __restrict__ C,
        int N, int K, float scale, const float* bias, const float* res, int relu,
        int cf32, int m_base, int aoff, int coff) {
    __shared__ __attribute__((aligned(16))) ushort_t As[64 * 32];
    __shared__ __attribute__((aligned(16))) ushort_t Bs[64 * 32];
    gemm_body<2, 2>(A, BT, C, N, K, scale, bias, res, relu, cf32, As, Bs,
                    m_base + blockIdx.x * 64, blockIdx.y * 64, aoff, coff);
}

__global__ __launch_bounds__(256) void gemm_qkv(const ushort_t* __restrict__ A,
        const ushort_t* __restrict__ wqT, const ushort_t* __restrict__ wkT,
        const ushort_t* __restrict__ wvT,
        ushort_t* __restrict__ Q, ushort_t* __restrict__ Kb, ushort_t* __restrict__ V) {
    __shared__ __attribute__((aligned(16))) ushort_t As[128 * 32];
    __shared__ __attribute__((aligned(16))) ushort_t Bs[128 * 32];
    int z = blockIdx.z;
    const ushort_t* W = (z == 0) ? wqT : ((z == 1) ? wkT : wvT);
    ushort_t* O = (z == 0) ? Q : ((z == 1) ? Kb : V);
    // fold 1/sqrt(64) AND log2(e) into Q so attn can use raw v_exp_f32 (exp2)
    float sc = (z == 0) ? 0.18033688011112042f : 1.f;
    gemm_body<4, 4>(A, W, O, DMODEL, DMODEL, sc, nullptr, nullptr, 0, 0, As, Bs,
                    blockIdx.x * 128, blockIdx.y * 128, 0, 0);
}

// ---------------- flash attention v5: v4 + SGPR-pair cndmask mask apply ----
// 32 q/wave, 2 waves/block, key-split x2 (partial O + denom, combined later).
// In-register P transpose (permlane32/16_swap), denominator via ones-MFMA.
// Mask: mbT words are wave-uniform addresses -> scalar loads; apply is ONE
// v_cndmask_b32 with sgpr-pair condition per score element (was ~3 VALU ops
// + 2 vector loads per iter on the measured 51%-busy VALU pipe).
__global__ __launch_bounds__(128, 4) void attn_kernel(const ushort_t* __restrict__ Q,
        const ushort_t* __restrict__ K, const ushort_t* __restrict__ VT,
        const u64* __restrict__ mbT, ushort_t* __restrict__ Opart,
        float* __restrict__ lpart) {
    __shared__ __attribute__((aligned(16))) ushort_t Ks[2][32 * 64];  // keys x d
    __shared__ __attribute__((aligned(16))) ushort_t Vs[2][64 * 32];  // d x keys
    int qt = blockIdx.x, h = blockIdx.y, zz = blockIdx.z;
    int b = zz >> 1, half = zz & 1;
    int tid = threadIdx.x;
    int wv = __builtin_amdgcn_readfirstlane(tid >> 6);   // SGPR wave id
    int lane = tid & 63;
    int lr = lane & 15, lg = lane >> 4;
    size_t tokbase = (size_t)b * S_LEN;
    int q0 = qt * 64 + wv * 32;
    int k0 = half * (S_LEN / 2);

    const ushort_t* Qp = Q + (tokbase + q0) * DMODEL + h * DHEAD;
    short8 qf[2][2];
#pragma unroll
    for (int u = 0; u < 2; u++) {
        qf[u][0] = *(const short8*)(Qp + (size_t)(u * 16 + lr) * DMODEL + lg * 8);
        qf[u][1] = *(const short8*)(Qp + (size_t)(u * 16 + lr) * DMODEL + 32 + lg * 8);
    }
    f32x4 o[2][4];
#pragma unroll
    for (int u = 0; u < 2; u++)
#pragma unroll
        for (int td = 0; td < 4; td++) o[u][td] = (f32x4){0.f, 0.f, 0.f, 0.f};
    f32x4 den[2] = {(f32x4){0.f, 0.f, 0.f, 0.f}, (f32x4){0.f, 0.f, 0.f, 0.f}};
    short8 ones8;
#pragma unroll
    for (int j = 0; j < 8; j++) ((ushort_t*)&ones8)[j] = 0x3F80;  // bf16 1.0

    int srow = lane >> 3, spos = lane & 7;      // K staging: 8 rows x 8 chunks
    int srow2 = lane >> 2, spos2 = lane & 3;    // V staging: 16 rows x 4 chunks
    int kst = (spos ^ srow) * 8;
    int vst = (spos2 ^ ((srow2 >> 1) & 3)) * 8;
    int rdk = lr & 7;
    int rdv = (lr >> 1) & 3;

    const ushort_t* kgl = K + (tokbase + k0) * DMODEL + h * DHEAD
                          + (size_t)srow * DMODEL + kst;
    const ushort_t* vgl = VT + (size_t)(b * NHEAD + h) * DHEAD * S_LEN
                          + (size_t)srow2 * S_LEN + k0 + vst;
    // wave-uniform mask-word base pointers (scalar-load path)
    const u64* mq0 = mbT + (((size_t)(q0 >> 4)) * 128 + half * 64) * 8;
    const u64* mq1 = mq0 + 128 * 8;

    // prologue: tile 0 into buf 0 (wave-split loads)
    if (wv == 0) {
        glds16(kgl + (size_t)0 * DMODEL, &Ks[0][0 * 64]);
        glds16(kgl + (size_t)8 * DMODEL, &Ks[0][8 * 64]);
        glds16(vgl + (size_t)0 * S_LEN, &Vs[0][0 * 32]);
        glds16(vgl + (size_t)16 * S_LEN, &Vs[0][16 * 32]);
    } else {
        glds16(kgl + (size_t)16 * DMODEL, &Ks[0][16 * 64]);
        glds16(kgl + (size_t)24 * DMODEL, &Ks[0][24 * 64]);
        glds16(vgl + (size_t)32 * S_LEN, &Vs[0][32 * 32]);
        glds16(vgl + (size_t)48 * S_LEN, &Vs[0][48 * 32]);
    }

    const int NIT = (S_LEN / 2) / 32;   // 64
#pragma unroll 1
    for (int kt = 0; kt < NIT; kt++) {
        int cur = kt & 1;
        // mask words for this tile: uniform address -> s_load; issue early
        const u64* m0 = mq0 + (size_t)kt * 8;
        const u64* m1 = mq1 + (size_t)kt * 8;
        __builtin_amdgcn_s_barrier();   // partner done reading buf cur^1 -> may overwrite
        if (kt + 1 < NIT) {
            const ushort_t* kgn = kgl + (size_t)(kt + 1) * 32 * DMODEL;
            const ushort_t* vgn = vgl + (kt + 1) * 32;
            if (wv == 0) {
                glds16(kgn + (size_t)0 * DMODEL, &Ks[cur ^ 1][0 * 64]);
                glds16(kgn + (size_t)8 * DMODEL, &Ks[cur ^ 1][8 * 64]);
                glds16(vgn + (size_t)0 * S_LEN, &Vs[cur ^ 1][0 * 32]);
                glds16(vgn + (size_t)16 * S_LEN, &Vs[cur ^ 1][16 * 32]);
            } else {
                glds16(kgn + (size_t)16 * DMODEL, &Ks[cur ^ 1][16 * 64]);
                glds16(kgn + (size_t)24 * DMODEL, &Ks[cur ^ 1][24 * 64]);
                glds16(vgn + (size_t)32 * S_LEN, &Vs[cur ^ 1][32 * 32]);
                glds16(vgn + (size_t)48 * S_LEN, &Vs[cur ^ 1][48 * 32]);
            }
            __builtin_amdgcn_s_waitcnt(3956);   // vmcnt(4): own tile-kt glds drained
        } else {
            __builtin_amdgcn_s_waitcnt(3952);   // vmcnt(0)
        }
        __builtin_amdgcn_s_barrier();   // partner's tile-kt loads visible in LDS
        const ushort_t* Kb_ = Ks[cur];
        const ushort_t* Vb_ = Vs[cur];
        // S^T = K Q^T : D[key][q]; col=q=u*16+lr, row=key=t*16+lg*4+r
        f32x4 s[2][2];
#pragma unroll
        for (int t = 0; t < 2; t++) {
            const ushort_t* kr = Kb_ + (t * 16 + lr) * 64;
            short8 kf0 = *(const short8*)(kr + ((lg ^ rdk) * 8));
            short8 kf1 = *(const short8*)(kr + (((lg + 4) ^ rdk) * 8));
#pragma unroll
            for (int u = 0; u < 2; u++) {
                f32x4 z = (f32x4){0.f, 0.f, 0.f, 0.f};
                z = __builtin_amdgcn_mfma_f32_16x16x32_bf16(kf0, qf[u][0], z, 0, 0, 0);
                z = __builtin_amdgcn_mfma_f32_16x16x32_bf16(kf1, qf[u][1], z, 0, 0, 0);
                s[t][u] = z;
            }
        }
        // exp2 (log2e folded into Q), mask via sgpr-pair cndmask
#pragma unroll
        for (int u = 0; u < 2; u++) {
            const u64* mu = u ? m1 : m0;
#pragma unroll
            for (int r = 0; r < 4; r++) {
                float p0, p1;
                asm("v_exp_f32 %0, %1\n\ts_nop 0" : "=v"(p0) : "v"(s[0][u][r]));
                asm("v_exp_f32 %0, %1\n\ts_nop 0" : "=v"(p1) : "v"(s[1][u][r]));
                asm("v_cndmask_b32 %0, 0, %1, %2" : "=v"(p0) : "v"(p0), "s"(mu[r]));
                asm("v_cndmask_b32 %0, 0, %1, %2" : "=v"(p1) : "v"(p1), "s"(mu[4 + r]));
                s[0][u][r] = p0; s[1][u][r] = p1;
            }
        }
        // V fragments (shared by both q-groups)
        short8 vf[4];
#pragma unroll
        for (int td = 0; td < 4; td++)
            vf[td] = *(const short8*)(Vb_ + (td * 16 + lr) * 32 + ((lg ^ rdv) * 8));
        // In-register P transpose: C-layout (4 keys @ lg*4, per t) ->
        // A-operand layout (8 keys @ g*8) via permlane32_swap + permlane16_swap.
#pragma unroll
        for (int u = 0; u < 2; u++) {
            unsigned c00, c01, c10, c11;
            asm("v_cvt_pk_bf16_f32 %0, %1, %2" : "=v"(c00) : "v"(s[0][u][0]), "v"(s[0][u][1]));
            asm("v_cvt_pk_bf16_f32 %0, %1, %2" : "=v"(c01) : "v"(s[0][u][2]), "v"(s[0][u][3]));
            asm("v_cvt_pk_bf16_f32 %0, %1, %2" : "=v"(c10) : "v"(s[1][u][0]), "v"(s[1][u][1]));
            asm("v_cvt_pk_bf16_f32 %0, %1, %2" : "=v"(c11) : "v"(s[1][u][2]), "v"(s[1][u][3]));
            auto r0 = __builtin_amdgcn_permlane32_swap(c00, c10, false, false);
            auto r1 = __builtin_amdgcn_permlane32_swap(c01, c11, false, false);
            auto p0 = __builtin_amdgcn_permlane16_swap(r0[0], r0[1], false, false);
            auto p1 = __builtin_amdgcn_permlane16_swap(r1[0], r1[1], false, false);
            union { unsigned u32[4]; short8 s8; } pk;
            pk.u32[0] = p0[0]; pk.u32[1] = p1[0]; pk.u32[2] = p0[1]; pk.u32[3] = p1[1];
            short8 pf = pk.s8;
            // O += P V ; den += P * ones (denominator in O-row layout)
#pragma unroll
            for (int td = 0; td < 4; td++)
                o[u][td] = __builtin_amdgcn_mfma_f32_16x16x32_bf16(pf, vf[td], o[u][td], 0, 0, 0);
            den[u] = __builtin_amdgcn_mfma_f32_16x16x32_bf16(pf, ones8, den[u], 0, 0, 0);
        }
    }
    // epilogue: store partial denom (row layout: q = u*16 + lg*4 + r, all 16
    // col-lanes hold copies -> store from lr==0) and unnormalized partial O.
    float* lp = lpart + (size_t)half * (NHEAD * 2 * S_LEN)
                + (size_t)(b * NHEAD + h) * S_LEN + q0;
    if (lr == 0) {
#pragma unroll
        for (int u = 0; u < 2; u++)
#pragma unroll
            for (int r = 0; r < 4; r++)
                lp[u * 16 + lg * 4 + r] = den[u][r];
    }
    ushort_t* Op = Opart + (size_t)half * NTOK * DMODEL;
#pragma unroll
    for (int u = 0; u < 2; u++) {
        size_t rowb = (tokbase + q0 + u * 16 + lg * 4) * DMODEL + h * DHEAD;
#pragma unroll
        for (int td = 0; td < 4; td++) {
            int cc = td * 16 + lr;
            Op[rowb + 0 * DMODEL + cc] = f2bf(o[u][td][0]);
            Op[rowb + 1 * DMODEL + cc] = f2bf(o[u][td][1]);
            Op[rowb + 2 * DMODEL + cc] = f2bf(o[u][td][2]);
            Op[rowb + 3 * DMODEL + cc] = f2bf(o[u][td][3]);
        }
    }
}

// ---------------- combine the two key-halves: ctx = (Oa+Ob)/(la+lb) ----------------
__global__ __launch_bounds__(256) void attn_combine(const ushort_t* __restrict__ Oa,
        const ushort_t* __restrict__ Ob, const float* __restrict__ la,
        const float* __restrict__ lb, ushort_t* __restrict__ ctx) {
    size_t idx = ((size_t)blockIdx.x * 256 + threadIdx.x) * 8;
    size_t tok = idx >> 9;
    int col = (int)(idx & 511);
    int h = col >> 6;
    int b = (int)(tok >> 12);
    int q = (int)(tok & 4095);
    size_t li = (size_t)(b * NHEAD + h) * S_LEN + q;
    float inv = 1.f / (la[li] + lb[li]);
    short8 va = *(const short8*)(Oa + idx);
    short8 vb = *(const short8*)(Ob + idx);
    short8 oo;
#pragma unroll
    for (int j = 0; j < 8; j++)
        ((ushort_t*)&oo)[j] = f2bf((bf2f(((const ushort_t*)&va)[j])
                                  + bf2f(((const ushort_t*)&vb)[j])) * inv);
    *(short8*)(ctx + idx) = oo;
}

extern "C" void kernel_launch(void* const* d_in, const int* in_sizes, int n_in,
                              void* d_out, int out_size, void* d_ws, size_t ws_size,
                              hipStream_t stream) {
    (void)in_sizes; (void)n_in; (void)out_size; (void)ws_size;
    const float* x    = (const float*)d_in[0];
    const int*   mask = (const int*)d_in[1];
    const float* w_q  = (const float*)d_in[2];
    const float* w_k  = (const float*)d_in[3];
    const float* w_v  = (const float*)d_in[4];
    const float* w_o  = (const float*)d_in[5];
    const float* w1   = (const float*)d_in[6];
    const float* b1   = (const float*)d_in[7];
    const float* w2   = (const float*)d_in[8];
    const float* b2   = (const float*)d_in[9];
    const float* l1a  = (const float*)d_in[10];
    const float* l1b  = (const float*)d_in[11];
    const float* l2a  = (const float*)d_in[12];
    const float* l2b  = (const float*)d_in[13];

    char* ws = (char*)d_ws;
    const size_t MB = 1024 * 1024;
    const size_t KB = 1024;
    // ---- layout, <= 54 MB ----
    ushort_t* w1T  = (ushort_t*)(ws + 0);               // 2MB
    ushort_t* w2T  = (ushort_t*)(ws + 2 * MB);          // 2MB
    ushort_t* wqT  = (ushort_t*)(ws + 4 * MB);          // 512KB (dead after QKV -> lpart)
    ushort_t* wkT  = (ushort_t*)(ws + 4 * MB + 512 * KB);
    ushort_t* wvT  = (ushort_t*)(ws + 5 * MB);
    ushort_t* woT  = (ushort_t*)(ws + 5 * MB + 512 * KB);
    ushort_t* ff1  = (ushort_t*)(ws + 6 * MB);          // 16MB: Opart (attn), then FFN chunk
    ushort_t* h    = (ushort_t*)(ws + 22 * MB);         // 8MB: h / VTb / h2
    ushort_t* VTb  = h;
    ushort_t* h2   = h;
    ushort_t* Qb   = (ushort_t*)(ws + 30 * MB);         // 8MB
    float*    x2f  = (float*)(ws + 30 * MB);            // 16MB (after attn)
    ushort_t* Kb   = (ushort_t*)(ws + 38 * MB);         // 8MB
    ushort_t* Vb   = (ushort_t*)(ws + 46 * MB);         // 8MB: V, then ctx
    ushort_t* ctx  = Vb;
    ushort_t* Opart = ff1;                              // 2 x 8MB bf16 partials
    float*    lpart = (float*)wqT;                      // 2 x 256KB f32 partial denoms
    u64*      mb   = (u64*)d_out;                       // 2MB scratch in d_out
    u64*      mbT  = (u64*)((char*)d_out + 2 * MB);     // 2MB lane-transposed words
    float*    out  = (float*)d_out;

    dim3 blk(256);
    maskbits_kernel<<<dim3(65536), blk, 0, stream>>>(mask, mb);
    masktrans_kernel<<<dim3(8192), blk, 0, stream>>>(mb, mbT);
    wtrans_all<<<dim3(32, 32, 6), blk, 0, stream>>>(w_q, w_k, w_v, w_o, w1, w2,
            wqT, wkT, wvT, woT, w1T, w2T);
    ln_f32<<<dim3(NTOK / 4), blk, 0, stream>>>(x, l1a, l1b, h);
    gemm_qkv<<<dim3(64, 4, 3), blk, 0, stream>>>(h, wqT, wkT, wvT, Qb, Kb, Vb);
    vtrans<<<dim3(64, 16), blk, 0, stream>>>(Vb, VTb);
    attn_kernel<<<dim3(64, 8, 4), dim3(128), 0, stream>>>(Qb, Kb, VTb,
            mbT, Opart, lpart);
    attn_combine<<<dim3(2048), blk, 0, stream>>>(Opart,
            Opart + (size_t)NTOK * DMODEL, lpart, lpart + NHEAD * 2 * S_LEN, ctx);
    gemm_bt64<<<dim3(128, 8), blk, 0, stream>>>(ctx, woT, x2f, 512, 512, 1.f,
            nullptr, x, 0, 1, 0, 0, 0);
    ln_f32<<<dim3(NTOK / 4), blk, 0, stream>>>(x2f, l2a, l2b, h2);
    gemm_bt64<<<dim3(64, 32), blk, 0, stream>>>(h2, w1T, ff1, 2048, 512, 1.f,
            b1, nullptr, 1, 0, 0, 0, 0);
    gemm_bt64<<<dim3(64, 8), blk, 0, stream>>>(ff1, w2T, out, 512, 2048, 1.f,
            b2, x2f, 0, 1, 0, 0, 0);
    gemm_bt64<<<dim3(64, 32), blk, 0, stream>>>(h2, w1T, ff1, 2048, 512, 1.f,
            b1, nullptr, 1, 0, 4096, 0, 4096);
    gemm_bt64<<<dim3(64, 8), blk, 0, stream>>>(ff1, w2T, out, 512, 2048, 1.f,
            b2, x2f, 0, 1, 4096, 4096, 0);
}

// Round 5
// 410.812 us; speedup vs baseline: 1.1315x; 1.0015x over previous
//
#include <hip/hip_runtime.h>
#include <hip/hip_bf16.h>
#include <stdint.h>

#define S_LEN 4096
#define DMODEL 512
#define NHEAD 8
#define DHEAD 64
#define NTOK 8192

typedef unsigned short ushort_t;
typedef __attribute__((ext_vector_type(8))) short short8;
typedef __attribute__((ext_vector_type(4))) float f32x4;
typedef unsigned long long u64;
typedef __attribute__((ext_vector_type(2))) unsigned uint2v;

__device__ __forceinline__ float bf2f(ushort_t h) {
    union { unsigned u; float f; } c; c.u = ((unsigned)h) << 16; return c.f;
}
__device__ __forceinline__ ushort_t f2bf(float f) {
    union { float f; unsigned u; } c; c.f = f;
    unsigned u = c.u + 0x7fffu + ((c.u >> 16) & 1u);
    return (ushort_t)(u >> 16);
}
// async global->LDS, 16B/lane; LDS dest MUST be a wave-uniform expression
// not derived from threadIdx (R10 lesson: wave-indexed LDS base -> ~27x stall).
__device__ __forceinline__ void glds16(const ushort_t* g, ushort_t* l) {
    __builtin_amdgcn_global_load_lds(
        (const __attribute__((address_space(1))) unsigned int*)g,
        (__attribute__((address_space(3))) unsigned int*)l, 16, 0, 0);
}

// ---------------- mask -> bit words ----------------
__global__ __launch_bounds__(256) void maskbits_kernel(const int* __restrict__ mask,
        u64* __restrict__ mb) {
    size_t id = (size_t)blockIdx.x * 256 + threadIdx.x;
    int v = mask[id];
    u64 bits = __ballot(v != 0);
    if ((threadIdx.x & 63) == 0) mb[id >> 6] = bits;
}

// ---------------- mask bits -> lane-transposed words for SGPR cndmask ----------
// mbT[gq][kt][t*4+r]: u64 whose bit[lane] = mask[gq*16+(lane&15)][kt*32+t*16+(lane>>4)*4+r]
__global__ __launch_bounds__(256) void masktrans_kernel(const u64* __restrict__ mb,
        u64* __restrict__ mbT) {
    int wid = (int)(((size_t)blockIdx.x * 256 + threadIdx.x) >> 6);
    int lane = threadIdx.x & 63;
    int gq = wid >> 7, kt = wid & 127;
    int lr = lane & 15, lg = lane >> 4;
    int row = gq * 16 + lr;
    u64* outp = mbT + ((size_t)gq * 128 + kt) * 8;
#pragma unroll
    for (int t = 0; t < 2; t++)
#pragma unroll
        for (int r = 0; r < 4; r++) {
            int col = kt * 32 + t * 16 + lg * 4 + r;
            u64 w = mb[(size_t)row * 64 + (col >> 6)];
            u64 bb = __ballot((unsigned)((w >> (col & 63)) & 1));
            if (lane == t * 4 + r) outp[t * 4 + r] = bb;
        }
}

// ---------------- all weight transposes in one launch ----------------
__global__ __launch_bounds__(256) void wtrans_all(const float* __restrict__ wq,
        const float* __restrict__ wk, const float* __restrict__ wv,
        const float* __restrict__ wo, const float* __restrict__ w1,
        const float* __restrict__ w2,
        ushort_t* wqT, ushort_t* wkT, ushort_t* wvT, ushort_t* woT,
        ushort_t* w1T, ushort_t* w2T) {
    __shared__ __attribute__((aligned(16))) ushort_t t[64][72];
    int z = blockIdx.z;
    const float* src; ushort_t* dst; int R, C;
    switch (z) {
        case 0: src = wq; dst = wqT; R = 512;  C = 512;  break;
        case 1: src = wk; dst = wkT; R = 512;  C = 512;  break;
        case 2: src = wv; dst = wvT; R = 512;  C = 512;  break;
        case 3: src = wo; dst = woT; R = 512;  C = 512;  break;
        case 4: src = w1; dst = w1T; R = 512;  C = 2048; break;
        default: src = w2; dst = w2T; R = 2048; C = 512; break;
    }
    int r0 = blockIdx.x * 64, c0 = blockIdx.y * 64;
    if (r0 >= R || c0 >= C) return;
    int tid = threadIdx.x;
    for (int i = tid; i < 4096; i += 256) {
        int r = i >> 6, c = i & 63;
        t[r][c] = f2bf(src[(size_t)(r0 + r) * C + c0 + c]);
    }
    __syncthreads();
    for (int i = tid; i < 512; i += 256) {
        int c = i >> 3, rb = i & 7;
        short8 vv;
#pragma unroll
        for (int j = 0; j < 8; j++) ((ushort_t*)&vv)[j] = t[rb * 8 + j][c];
        *(short8*)(dst + (size_t)(c0 + c) * R + r0 + rb * 8) = vv;
    }
}

// ---------------- LayerNorm: f32 in, bf16 out; 4 tokens/block ----------------
__global__ __launch_bounds__(256) void ln_f32(const float* __restrict__ x,
        const float* __restrict__ ga, const float* __restrict__ be,
        ushort_t* __restrict__ out) {
    int tok = blockIdx.x * 4 + (threadIdx.x >> 6);
    int lane = threadIdx.x & 63;
    const float* xr = x + (size_t)tok * DMODEL + lane * 8;
    f32x4 v0 = *(const f32x4*)xr;
    f32x4 v1 = *(const f32x4*)(xr + 4);
    float f[8];
    float s = 0.f, s2 = 0.f;
#pragma unroll
    for (int i = 0; i < 8; i++) {
        f[i] = (i < 4) ? v0[i] : v1[i - 4];
        s += f[i]; s2 += f[i] * f[i];
    }
#pragma unroll
    for (int off = 1; off < 64; off <<= 1) {
        s += __shfl_xor(s, off);
        s2 += __shfl_xor(s2, off);
    }
    float mean = s * (1.f / DMODEL);
    float var = (s2 - (float)DMODEL * mean * mean) * (1.f / (DMODEL - 1));
    var = fmaxf(var, 0.f);
    float inv = 1.f / (sqrtf(var) + 1e-6f);   // torch: eps added to std, ddof=1
    short8 o;
#pragma unroll
    for (int i = 0; i < 8; i++) {
        float val = ga[lane * 8 + i] * (f[i] - mean) * inv + be[lane * 8 + i];
        ((ushort_t*)&o)[i] = f2bf(val);
    }
    *(short8*)(out + (size_t)tok * DMODEL + lane * 8) = o;
}

// ---------------- per-head V transpose: V[b,s,h*64+d] -> VT[bh][d][s] ----------------
__global__ __launch_bounds__(256) void vtrans(const ushort_t* __restrict__ V,
        ushort_t* __restrict__ VT) {
    __shared__ __attribute__((aligned(16))) ushort_t t[64][72];
    int s0 = blockIdx.x * 64;
    int bh = blockIdx.y;
    int b = bh >> 3, h = bh & 7;
    int tid = threadIdx.x;
    const ushort_t* src = V + ((size_t)b * S_LEN + s0) * DMODEL + h * DHEAD;
    for (int i = tid; i < 512; i += 256) {
        int r = i >> 3, cb = i & 7;
        *(short8*)&t[r][cb * 8] = *(const short8*)(src + (size_t)r * DMODEL + cb * 8);
    }
    __syncthreads();
    ushort_t* dst = VT + (size_t)bh * DHEAD * S_LEN;
    for (int i = tid; i < 512; i += 256) {
        int d = i >> 3, rb = i & 7;
        short8 vv;
#pragma unroll
        for (int j = 0; j < 8; j++) ((ushort_t*)&vv)[j] = t[rb * 8 + j][d];
        *(short8*)(dst + (size_t)d * S_LEN + s0 + rb * 8) = vv;
    }
}

// ---------------- bf16 GEMM core, BK=64: block = (32*MW) x (32*NW) ----------------
// K-staging uses the attn kernel's proven 8-row/8-chunk XOR swizzle
// ((spos^srow)*8 write, (lg|lg+4)^(lr&7) read): conflict-free, and per
// barrier-pair each wave now issues 2*MW*NW MFMA (was MW*NW) -> half the
// barrier/vmcnt-drain stalls of the BK=32 structure.
template <int MW, int NW>
__device__ __forceinline__ void gemm_body(const ushort_t* __restrict__ A,
        const ushort_t* __restrict__ BT, void* __restrict__ C,
        int N, int K, float scale, const float* __restrict__ bias,
        const float* __restrict__ res, int relu, int cf32,
        ushort_t* As, ushort_t* Bs, int m0, int n0, int aoff, int coff) {
    int tid = threadIdx.x;
    int wave = tid >> 6, lane = tid & 63;
    int wm = wave >> 1, wn = wave & 1;
    int lr = lane & 15, lg = lane >> 4;
    int srow = lane >> 3, spos = lane & 7;
    int kst = (spos ^ srow) * 8;
    int rdk = lr & 7;
    f32x4 acc[MW][NW];
#pragma unroll
    for (int i = 0; i < MW; i++)
#pragma unroll
        for (int j = 0; j < NW; j++) acc[i][j] = (f32x4){0.f, 0.f, 0.f, 0.f};

    const ushort_t* Ag = A + (size_t)(m0 - aoff) * K;
    const ushort_t* Bg = BT + (size_t)n0 * K;

    for (int k0 = 0; k0 < K; k0 += 64) {
        __syncthreads();
        for (int ia = wave; ia < 4 * MW; ia += 4)
            glds16(Ag + (size_t)(ia * 8 + srow) * K + k0 + kst, As + ia * 8 * 64);
        for (int ib = wave; ib < 4 * NW; ib += 4)
            glds16(Bg + (size_t)(ib * 8 + srow) * K + k0 + kst, Bs + ib * 8 * 64);
        __syncthreads();
        short8 af[MW][2], bfv[NW][2];
#pragma unroll
        for (int t = 0; t < MW; t++) {
            const ushort_t* ar = As + (size_t)(wm * 16 * MW + t * 16 + lr) * 64;
            af[t][0] = *(const short8*)(ar + ((lg ^ rdk) * 8));
            af[t][1] = *(const short8*)(ar + (((lg + 4) ^ rdk) * 8));
        }
#pragma unroll
        for (int t = 0; t < NW; t++) {
            const ushort_t* br = Bs + (size_t)(wn * 16 * NW + t * 16 + lr) * 64;
            bfv[t][0] = *(const short8*)(br + ((lg ^ rdk) * 8));
            bfv[t][1] = *(const short8*)(br + (((lg + 4) ^ rdk) * 8));
        }
#pragma unroll
        for (int i = 0; i < MW; i++)
#pragma unroll
            for (int j = 0; j < NW; j++) {
                acc[i][j] = __builtin_amdgcn_mfma_f32_16x16x32_bf16(af[i][0], bfv[j][0], acc[i][j], 0, 0, 0);
                acc[i][j] = __builtin_amdgcn_mfma_f32_16x16x32_bf16(af[i][1], bfv[j][1], acc[i][j], 0, 0, 0);
            }
    }
#pragma unroll
    for (int i = 0; i < MW; i++) {
        int row = m0 + wm * 16 * MW + i * 16 + lg * 4;
#pragma unroll
        for (int j = 0; j < NW; j++) {
            int col = n0 + wn * 16 * NW + j * 16 + lr;
            float bb = bias ? bias[col] : 0.f;
#pragma unroll
            for (int r = 0; r < 4; r++) {
                float v = acc[i][j][r] * scale + bb;
                if (relu) v = fmaxf(v, 0.f);
                if (res) v += res[(size_t)(row + r) * N + col];
                size_t cidx = (size_t)(row + r - coff) * N + col;
                if (cf32) ((float*)C)[cidx] = v;
                else      ((ushort_t*)C)[cidx] = f2bf(v);
            }
        }
    }
}

__global__ __launch_bounds__(256) void gemm_bt64(const ushort_t* __restrict__ A,
        const ushort_t* __restrict__ BT, void* __restrict__ C,
        int N, int K, float scale, const float* bias, const float* res, int relu,
        int cf32, int m_base, int aoff, int coff) {
    __shared__ __attribute__((aligned(16))) ushort_t As[64 * 64];
    __shared__ __attribute__((aligned(16))) ushort_t Bs[64 * 64];
    gemm_body<2, 2>(A, BT, C, N, K, scale, bias, res, relu, cf32, As, Bs,
                    m_base + blockIdx.x * 64, blockIdx.y * 64, aoff, coff);
}

__global__ __launch_bounds__(256) void gemm_qkv(const ushort_t* __restrict__ A,
        const ushort_t* __restrict__ wqT, const ushort_t* __restrict__ wkT,
        const ushort_t* __restrict__ wvT,
        ushort_t* __restrict__ Q, ushort_t* __restrict__ Kb, ushort_t* __restrict__ V) {
    __shared__ __attribute__((aligned(16))) ushort_t As[128 * 64];
    __shared__ __attribute__((aligned(16))) ushort_t Bs[128 * 64];
    int z = blockIdx.z;
    const ushort_t* W = (z == 0) ? wqT : ((z == 1) ? wkT : wvT);
    ushort_t* O = (z == 0) ? Q : ((z == 1) ? Kb : V);
    // fold 1/sqrt(64) AND log2(e) into Q so attn can use raw v_exp_f32 (exp2)
    float sc = (z == 0) ? 0.18033688011112042f : 1.f;
    gemm_body<4, 4>(A, W, O, DMODEL, DMODEL, sc, nullptr, nullptr, 0, 0, As, Bs,
                    blockIdx.x * 128, blockIdx.y * 128, 0, 0);
}

// ---------------- flash attention v6: v5 + s_setprio around compute phase ----
__global__ __launch_bounds__(128, 4) void attn_kernel(const ushort_t* __restrict__ Q,
        const ushort_t* __restrict__ K, const ushort_t* __restrict__ VT,
        const u64* __restrict__ mbT, ushort_t* __restrict__ Opart,
        float* __restrict__ lpart) {
    __shared__ __attribute__((aligned(16))) ushort_t Ks[2][32 * 64];  // keys x d
    __shared__ __attribute__((aligned(16))) ushort_t Vs[2][64 * 32];  // d x keys
    int qt = blockIdx.x, h = blockIdx.y, zz = blockIdx.z;
    int b = zz >> 1, half = zz & 1;
    int tid = threadIdx.x;
    int wv = __builtin_amdgcn_readfirstlane(tid >> 6);   // SGPR wave id
    int lane = tid & 63;
    int lr = lane & 15, lg = lane >> 4;
    size_t tokbase = (size_t)b * S_LEN;
    int q0 = qt * 64 + wv * 32;
    int k0 = half * (S_LEN / 2);

    const ushort_t* Qp = Q + (tokbase + q0) * DMODEL + h * DHEAD;
    short8 qf[2][2];
#pragma unroll
    for (int u = 0; u < 2; u++) {
        qf[u][0] = *(const short8*)(Qp + (size_t)(u * 16 + lr) * DMODEL + lg * 8);
        qf[u][1] = *(const short8*)(Qp + (size_t)(u * 16 + lr) * DMODEL + 32 + lg * 8);
    }
    f32x4 o[2][4];
#pragma unroll
    for (int u = 0; u < 2; u++)
#pragma unroll
        for (int td = 0; td < 4; td++) o[u][td] = (f32x4){0.f, 0.f, 0.f, 0.f};
    f32x4 den[2] = {(f32x4){0.f, 0.f, 0.f, 0.f}, (f32x4){0.f, 0.f, 0.f, 0.f}};
    short8 ones8;
#pragma unroll
    for (int j = 0; j < 8; j++) ((ushort_t*)&ones8)[j] = 0x3F80;  // bf16 1.0

    int srow = lane >> 3, spos = lane & 7;      // K staging: 8 rows x 8 chunks
    int srow2 = lane >> 2, spos2 = lane & 3;    // V staging: 16 rows x 4 chunks
    int kst = (spos ^ srow) * 8;
    int vst = (spos2 ^ ((srow2 >> 1) & 3)) * 8;
    int rdk = lr & 7;
    int rdv = (lr >> 1) & 3;

    const ushort_t* kgl = K + (tokbase + k0) * DMODEL + h * DHEAD
                          + (size_t)srow * DMODEL + kst;
    const ushort_t* vgl = VT + (size_t)(b * NHEAD + h) * DHEAD * S_LEN
                          + (size_t)srow2 * S_LEN + k0 + vst;
    // wave-uniform mask-word base pointers (scalar-load path)
    const u64* mq0 = mbT + (((size_t)(q0 >> 4)) * 128 + half * 64) * 8;
    const u64* mq1 = mq0 + 128 * 8;

    // prologue: tile 0 into buf 0 (wave-split loads)
    if (wv == 0) {
        glds16(kgl + (size_t)0 * DMODEL, &Ks[0][0 * 64]);
        glds16(kgl + (size_t)8 * DMODEL, &Ks[0][8 * 64]);
        glds16(vgl + (size_t)0 * S_LEN, &Vs[0][0 * 32]);
        glds16(vgl + (size_t)16 * S_LEN, &Vs[0][16 * 32]);
    } else {
        glds16(kgl + (size_t)16 * DMODEL, &Ks[0][16 * 64]);
        glds16(kgl + (size_t)24 * DMODEL, &Ks[0][24 * 64]);
        glds16(vgl + (size_t)32 * S_LEN, &Vs[0][32 * 32]);
        glds16(vgl + (size_t)48 * S_LEN, &Vs[0][48 * 32]);
    }

    const int NIT = (S_LEN / 2) / 32;   // 64
#pragma unroll 1
    for (int kt = 0; kt < NIT; kt++) {
        int cur = kt & 1;
        // mask words for this tile: uniform address -> s_load; issue early
        const u64* m0 = mq0 + (size_t)kt * 8;
        const u64* m1 = mq1 + (size_t)kt * 8;
        __builtin_amdgcn_s_barrier();   // partner done reading buf cur^1 -> may overwrite
        if (kt + 1 < NIT) {
            const ushort_t* kgn = kgl + (size_t)(kt + 1) * 32 * DMODEL;
            const ushort_t* vgn = vgl + (kt + 1) * 32;
            if (wv == 0) {
                glds16(kgn + (size_t)0 * DMODEL, &Ks[cur ^ 1][0 * 64]);
                glds16(kgn + (size_t)8 * DMODEL, &Ks[cur ^ 1][8 * 64]);
                glds16(vgn + (size_t)0 * S_LEN, &Vs[cur ^ 1][0 * 32]);
                glds16(vgn + (size_t)16 * S_LEN, &Vs[cur ^ 1][16 * 32]);
            } else {
                glds16(kgn + (size_t)16 * DMODEL, &Ks[cur ^ 1][16 * 64]);
                glds16(kgn + (size_t)24 * DMODEL, &Ks[cur ^ 1][24 * 64]);
                glds16(vgn + (size_t)32 * S_LEN, &Vs[cur ^ 1][32 * 32]);
                glds16(vgn + (size_t)48 * S_LEN, &Vs[cur ^ 1][48 * 32]);
            }
            __builtin_amdgcn_s_waitcnt(3956);   // vmcnt(4): own tile-kt glds drained
        } else {
            __builtin_amdgcn_s_waitcnt(3952);   // vmcnt(0)
        }
        __builtin_amdgcn_s_barrier();   // partner's tile-kt loads visible in LDS
        __builtin_amdgcn_s_setprio(1);  // favor this wave's compute over co-resident
        const ushort_t* Kb_ = Ks[cur];
        const ushort_t* Vb_ = Vs[cur];
        // S^T = K Q^T : D[key][q]; col=q=u*16+lr, row=key=t*16+lg*4+r
        f32x4 s[2][2];
#pragma unroll
        for (int t = 0; t < 2; t++) {
            const ushort_t* kr = Kb_ + (t * 16 + lr) * 64;
            short8 kf0 = *(const short8*)(kr + ((lg ^ rdk) * 8));
            short8 kf1 = *(const short8*)(kr + (((lg + 4) ^ rdk) * 8));
#pragma unroll
            for (int u = 0; u < 2; u++) {
                f32x4 z = (f32x4){0.f, 0.f, 0.f, 0.f};
                z = __builtin_amdgcn_mfma_f32_16x16x32_bf16(kf0, qf[u][0], z, 0, 0, 0);
                z = __builtin_amdgcn_mfma_f32_16x16x32_bf16(kf1, qf[u][1], z, 0, 0, 0);
                s[t][u] = z;
            }
        }
        // exp2 (log2e folded into Q), mask via sgpr-pair cndmask
#pragma unroll
        for (int u = 0; u < 2; u++) {
            const u64* mu = u ? m1 : m0;
#pragma unroll
            for (int r = 0; r < 4; r++) {
                float p0, p1;
                asm("v_exp_f32 %0, %1\n\ts_nop 0" : "=v"(p0) : "v"(s[0][u][r]));
                asm("v_exp_f32 %0, %1\n\ts_nop 0" : "=v"(p1) : "v"(s[1][u][r]));
                asm("v_cndmask_b32 %0, 0, %1, %2" : "=v"(p0) : "v"(p0), "s"(mu[r]));
                asm("v_cndmask_b32 %0, 0, %1, %2" : "=v"(p1) : "v"(p1), "s"(mu[4 + r]));
                s[0][u][r] = p0; s[1][u][r] = p1;
            }
        }
        // V fragments (shared by both q-groups)
        short8 vf[4];
#pragma unroll
        for (int td = 0; td < 4; td++)
            vf[td] = *(const short8*)(Vb_ + (td * 16 + lr) * 32 + ((lg ^ rdv) * 8));
        // In-register P transpose: C-layout (4 keys @ lg*4, per t) ->
        // A-operand layout (8 keys @ g*8) via permlane32_swap + permlane16_swap.
#pragma unroll
        for (int u = 0; u < 2; u++) {
            unsigned c00, c01, c10, c11;
            asm("v_cvt_pk_bf16_f32 %0, %1, %2" : "=v"(c00) : "v"(s[0][u][0]), "v"(s[0][u][1]));
            asm("v_cvt_pk_bf16_f32 %0, %1, %2" : "=v"(c01) : "v"(s[0][u][2]), "v"(s[0][u][3]));
            asm("v_cvt_pk_bf16_f32 %0, %1, %2" : "=v"(c10) : "v"(s[1][u][0]), "v"(s[1][u][1]));
            asm("v_cvt_pk_bf16_f32 %0, %1, %2" : "=v"(c11) : "v"(s[1][u][2]), "v"(s[1][u][3]));
            auto r0 = __builtin_amdgcn_permlane32_swap(c00, c10, false, false);
            auto r1 = __builtin_amdgcn_permlane32_swap(c01, c11, false, false);
            auto p0 = __builtin_amdgcn_permlane16_swap(r0[0], r0[1], false, false);
            auto p1 = __builtin_amdgcn_permlane16_swap(r1[0], r1[1], false, false);
            union { unsigned u32[4]; short8 s8; } pk;
            pk.u32[0] = p0[0]; pk.u32[1] = p1[0]; pk.u32[2] = p0[1]; pk.u32[3] = p1[1];
            short8 pf = pk.s8;
            // O += P V ; den += P * ones (denominator in O-row layout)
#pragma unroll
            for (int td = 0; td < 4; td++)
                o[u][td] = __builtin_amdgcn_mfma_f32_16x16x32_bf16(pf, vf[td], o[u][td], 0, 0, 0);
            den[u] = __builtin_amdgcn_mfma_f32_16x16x32_bf16(pf, ones8, den[u], 0, 0, 0);
        }
        __builtin_amdgcn_s_setprio(0);
    }
    // epilogue: store partial denom (row layout: q = u*16 + lg*4 + r, all 16
    // col-lanes hold copies -> store from lr==0) and unnormalized partial O.
    float* lp = lpart + (size_t)half * (NHEAD * 2 * S_LEN)
                + (size_t)(b * NHEAD + h) * S_LEN + q0;
    if (lr == 0) {
#pragma unroll
        for (int u = 0; u < 2; u++)
#pragma unroll
            for (int r = 0; r < 4; r++)
                lp[u * 16 + lg * 4 + r] = den[u][r];
    }
    ushort_t* Op = Opart + (size_t)half * NTOK * DMODEL;
#pragma unroll
    for (int u = 0; u < 2; u++) {
        size_t rowb = (tokbase + q0 + u * 16 + lg * 4) * DMODEL + h * DHEAD;
#pragma unroll
        for (int td = 0; td < 4; td++) {
            int cc = td * 16 + lr;
            Op[rowb + 0 * DMODEL + cc] = f2bf(o[u][td][0]);
            Op[rowb + 1 * DMODEL + cc] = f2bf(o[u][td][1]);
            Op[rowb + 2 * DMODEL + cc] = f2bf(o[u][td][2]);
            Op[rowb + 3 * DMODEL + cc] = f2bf(o[u][td][3]);
        }
    }
}

// ---------------- combine the two key-halves: ctx = (Oa+Ob)/(la+lb) ----------------
__global__ __launch_bounds__(256) void attn_combine(const ushort_t* __restrict__ Oa,
        const ushort_t* __restrict__ Ob, const float* __restrict__ la,
        const float* __restrict__ lb, ushort_t* __restrict__ ctx) {
    size_t idx = ((size_t)blockIdx.x * 256 + threadIdx.x) * 8;
    size_t tok = idx >> 9;
    int col = (int)(idx & 511);
    int h = col >> 6;
    int b = (int)(tok >> 12);
    int q = (int)(tok & 4095);
    size_t li = (size_t)(b * NHEAD + h) * S_LEN + q;
    float inv = 1.f / (la[li] + lb[li]);
    short8 va = *(const short8*)(Oa + idx);
    short8 vb = *(const short8*)(Ob + idx);
    short8 oo;
#pragma unroll
    for (int j = 0; j < 8; j++)
        ((ushort_t*)&oo)[j] = f2bf((bf2f(((const ushort_t*)&va)[j])
                                  + bf2f(((const ushort_t*)&vb)[j])) * inv);
    *(short8*)(ctx + idx) = oo;
}

extern "C" void kernel_launch(void* const* d_in, const int* in_sizes, int n_in,
                              void* d_out, int out_size, void* d_ws, size_t ws_size,
                              hipStream_t stream) {
    (void)in_sizes; (void)n_in; (void)out_size; (void)ws_size;
    const float* x    = (const float*)d_in[0];
    const int*   mask = (const int*)d_in[1];
    const float* w_q  = (const float*)d_in[2];
    const float* w_k  = (const float*)d_in[3];
    const float* w_v  = (const float*)d_in[4];
    const float* w_o  = (const float*)d_in[5];
    const float* w1   = (const float*)d_in[6];
    const float* b1   = (const float*)d_in[7];
    const float* w2   = (const float*)d_in[8];
    const float* b2   = (const float*)d_in[9];
    const float* l1a  = (const float*)d_in[10];
    const float* l1b  = (const float*)d_in[11];
    const float* l2a  = (const float*)d_in[12];
    const float* l2b  = (const float*)d_in[13];

    char* ws = (char*)d_ws;
    const size_t MB = 1024 * 1024;
    const size_t KB = 1024;
    // ---- layout, <= 54 MB ----
    ushort_t* w1T  = (ushort_t*)(ws + 0);               // 2MB
    ushort_t* w2T  = (ushort_t*)(ws + 2 * MB);          // 2MB
    ushort_t* wqT  = (ushort_t*)(ws + 4 * MB);          // 512KB (dead after QKV -> lpart)
    ushort_t* wkT  = (ushort_t*)(ws + 4 * MB + 512 * KB);
    ushort_t* wvT  = (ushort_t*)(ws + 5 * MB);
    ushort_t* woT  = (ushort_t*)(ws + 5 * MB + 512 * KB);
    ushort_t* ff1  = (ushort_t*)(ws + 6 * MB);          // 16MB: Opart (attn), then FFN chunk
    ushort_t* h    = (ushort_t*)(ws + 22 * MB);         // 8MB: h / VTb / h2
    ushort_t* VTb  = h;
    ushort_t* h2   = h;
    ushort_t* Qb   = (ushort_t*)(ws + 30 * MB);         // 8MB
    float*    x2f  = (float*)(ws + 30 * MB);            // 16MB (after attn)
    ushort_t* Kb   = (ushort_t*)(ws + 38 * MB);         // 8MB
    ushort_t* Vb   = (ushort_t*)(ws + 46 * MB);         // 8MB: V, then ctx
    ushort_t* ctx  = Vb;
    ushort_t* Opart = ff1;                              // 2 x 8MB bf16 partials
    float*    lpart = (float*)wqT;                      // 2 x 256KB f32 partial denoms
    u64*      mb   = (u64*)d_out;                       // 2MB scratch in d_out
    u64*      mbT  = (u64*)((char*)d_out + 2 * MB);     // 2MB lane-transposed words
    float*    out  = (float*)d_out;

    dim3 blk(256);
    maskbits_kernel<<<dim3(65536), blk, 0, stream>>>(mask, mb);
    masktrans_kernel<<<dim3(8192), blk, 0, stream>>>(mb, mbT);
    wtrans_all<<<dim3(32, 32, 6), blk, 0, stream>>>(w_q, w_k, w_v, w_o, w1, w2,
            wqT, wkT, wvT, woT, w1T, w2T);
    ln_f32<<<dim3(NTOK / 4), blk, 0, stream>>>(x, l1a, l1b, h);
    gemm_qkv<<<dim3(64, 4, 3), blk, 0, stream>>>(h, wqT, wkT, wvT, Qb, Kb, Vb);
    vtrans<<<dim3(64, 16), blk, 0, stream>>>(Vb, VTb);
    attn_kernel<<<dim3(64, 8, 4), dim3(128), 0, stream>>>(Qb, Kb, VTb,
            mbT, Opart, lpart);
    attn_combine<<<dim3(2048), blk, 0, stream>>>(Opart,
            Opart + (size_t)NTOK * DMODEL, lpart, lpart + NHEAD * 2 * S_LEN, ctx);
    gemm_bt64<<<dim3(128, 8), blk, 0, stream>>>(ctx, woT, x2f, 512, 512, 1.f,
            nullptr, x, 0, 1, 0, 0, 0);
    ln_f32<<<dim3(NTOK / 4), blk, 0, stream>>>(x2f, l2a, l2b, h2);
    gemm_bt64<<<dim3(64, 32), blk, 0, stream>>>(h2, w1T, ff1, 2048, 512, 1.f,
            b1, nullptr, 1, 0, 0, 0, 0);
    gemm_bt64<<<dim3(64, 8), blk, 0, stream>>>(ff1, w2T, out, 512, 2048, 1.f,
            b2, x2f, 0, 1, 0, 0, 0);
    gemm_bt64<<<dim3(64, 32), blk, 0, stream>>>(h2, w1T, ff1, 2048, 512, 1.f,
            b1, nullptr, 1, 0, 4096, 0, 4096);
    gemm_bt64<<<dim3(64, 8), blk, 0, stream>>>(ff1, w2T, out, 512, 2048, 1.f,
            b2, x2f, 0, 1, 4096, 4096, 0);
}